// Round 23
// baseline (196.730 us; speedup 1.0000x reference)
//
#include <hip/hip_runtime.h>
#include <hip/hip_bf16.h>
#include <math.h>

#define B_   4
#define C_   256
#define L_   8192
#define NH   8
#define HD   32
#define WIN  256
#define STR  192
#define NWIN 43
#define HID  1024

typedef short short8 __attribute__((ext_vector_type(8)));
typedef float f32x4  __attribute__((ext_vector_type(4)));

typedef __attribute__((address_space(3))) unsigned int       as3_u32;
typedef __attribute__((address_space(1))) const unsigned int as1_u32;

__device__ __forceinline__ void gll16(const void* g, void* l) {
    __builtin_amdgcn_global_load_lds((as1_u32*)g, (as3_u32*)l, 16, 0, 0);
}

__device__ __forceinline__ short f2b(float f) {          // f32 -> bf16 RNE
    unsigned u = __builtin_bit_cast(unsigned, f);
    u += 0x7fffu + ((u >> 16) & 1u);
    return (short)(u >> 16);
}
__device__ __forceinline__ float b2f(short s) {
    return __builtin_bit_cast(float, (unsigned)((unsigned short)s) << 16);
}
// single v_perm_b32: pack hi16(a)|hi16(b)<<16 (bf16 TRUNCATION; ~2^-8 rel)
__device__ __forceinline__ unsigned pkt(float a, float b) {
    return __builtin_amdgcn_perm(__builtin_bit_cast(unsigned, b),
                                 __builtin_bit_cast(unsigned, a),
                                 0x07060302u);
}
// tanh-form GELU, exp2-folded constants + raw v_rcp; |err| < ~1e-3
__device__ __forceinline__ float gelu_fast(float x) {
    float t = x * x;
    float u = fmaf(0.1029436f * t, x, 2.3022083f * x);   // coeffs * log2(e)
    return x * __builtin_amdgcn_rcpf(1.0f + __builtin_amdgcn_exp2f(-u));
}

// ---------------------------------------------------------------------------
// bf16 MFMA GEMM, 128x128 tile, BK=64 (2 kk sub-steps of K=32), 4 waves.
// LDS A/B [128 rows][8 chunks of 16B], chunk-swizzled phys = logical ^ (row&7)
// via pre-swizzled global source; LDS dest stays linear for global_load_lds.
// MODE 0: qkv  (M=768,K=256)  -> +bias (q pre-scaled log2e/sqrt32), bf16 qkv
// MODE 1: proj (M=256,K=256)  B = window-combine of win_out (fused comb)
//                             -> +bias+resid, f32 y; row (sum,ssq) atomics
// MODE 2: mlp1 (M=1024,K=256) -> gelu_fast(+bias), bf16 h_t [b][l][HID]
// MODE 3: mlp2 (M=256,K=1024) -> +bias, f32 d_out [b][C][l]
// ---------------------------------------------------------------------------
template<int MODE>
__global__ __launch_bounds__(256)
void mgemm(const short* __restrict__ Wb, const short* __restrict__ Xsrc,
           const float* __restrict__ bias, const float* __restrict__ resid,
           void* __restrict__ outp, float2* __restrict__ stt)
{
    constexpr int K = (MODE == 3) ? 1024 : 256;
    constexpr int M = (MODE == 0) ? 768 : (MODE == 2) ? 1024 : 256;
    constexpr int LDSZ = (MODE == 0 || MODE == 2) ? 34816 : 32768;
    __shared__ __align__(16) char lds[LDSZ];

    const int t    = threadIdx.x;
    const int lane = t & 63, wid = t >> 6;
    const int wm   = wid >> 1, wn = wid & 1;
    const int b    = blockIdx.z;
    const int o0   = blockIdx.y * 128;
    const int l0   = blockIdx.x * 128;
    const int l15  = lane & 15, kb = lane >> 4;

    f32x4 acc[4][4] = {};
    const short* Xb = Xsrc + (size_t)b * L_ * K;

    // MODE 1: per-staged-row window indices (independent of k)
    int pn1[4], pj1[4]; bool ptwo[4];
    if constexpr (MODE == 1) {
        #pragma unroll
        for (int it = 0; it < 4; ++it) {
            int r = (it * 256 + t) >> 3;
            int l = l0 + r;
            int n1 = l / STR;
            pn1[it] = n1; pj1[it] = l - n1 * STR;
            ptwo[it] = (n1 >= 1) && (pj1[it] < WIN - STR);
        }
    }

    for (int c0 = 0; c0 < K; c0 += 64) {
        __syncthreads();
        // ---- stage A (weights) ----
        #pragma unroll
        for (int it = 0; it < 4; ++it) {
            int d = it * 256 + t;
            int r = d >> 3, pc = d & 7;
            int clog = pc ^ (r & 7);
            gll16(Wb + (size_t)(o0 + r) * K + c0 + clog * 8,
                  lds + (it * 256 + wid * 64) * 16);
        }
        // ---- stage B ----
        if constexpr (MODE == 1) {
            #pragma unroll
            for (int it = 0; it < 4; ++it) {
                int d = it * 256 + t;
                int r = d >> 3, pc = d & 7;
                int clog = pc ^ (r & 7);
                int c = c0 + clog * 8;
                int h = c >> 5, dd = c & 31;
                size_t base = ((((size_t)(b * NH + h)) * NWIN + pn1[it]) * WIN + pj1[it]) * HD + dd;
                short8 vv = *(const short8*)&Xsrc[base];
                if (ptwo[it]) {
                    short8 u = *(const short8*)&Xsrc[base - 2048];  // (n1-1, j1+192)
                    #pragma unroll
                    for (int e = 0; e < 8; ++e) vv[e] = f2b(b2f(vv[e]) + b2f(u[e]));
                }
                *(short8*)(lds + 16384 + d * 16) = vv;
            }
        } else {
            #pragma unroll
            for (int it = 0; it < 4; ++it) {
                int d = it * 256 + t;
                int r = d >> 3, pc = d & 7;
                int clog = pc ^ (r & 7);
                gll16(Xb + (size_t)(l0 + r) * K + c0 + clog * 8,
                      lds + 16384 + (it * 256 + wid * 64) * 16);
            }
        }
        __syncthreads();
        // ---- compute: 2 kk sub-steps of 16 MFMA ----
        #pragma unroll
        for (int kk = 0; kk < 2; ++kk) {
            short8 af[4], bf[4];
            #pragma unroll
            for (int i = 0; i < 4; ++i)
                af[i] = *(const short8*)(lds +
                    ((wm * 64 + i * 16 + l15) * 8 + ((kk * 4 + kb) ^ (l15 & 7))) * 16);
            #pragma unroll
            for (int j = 0; j < 4; ++j)
                bf[j] = *(const short8*)(lds + 16384 +
                    ((wn * 64 + j * 16 + l15) * 8 + ((kk * 4 + kb) ^ (l15 & 7))) * 16);
            #pragma unroll
            for (int i = 0; i < 4; ++i)
                #pragma unroll
                for (int j = 0; j < 4; ++j)
                    acc[i][j] = __builtin_amdgcn_mfma_f32_16x16x32_bf16(af[i], bf[j], acc[i][j], 0, 0, 0);
        }
    }

    const int orow = (lane >> 4) * 4;

    if constexpr (MODE == 1 || MODE == 3) {
        float* out = (float*)outp;
        #pragma unroll
        for (int i = 0; i < 4; ++i) {
            #pragma unroll
            for (int r = 0; r < 4; ++r) {
                const int o = o0 + wm * 64 + i * 16 + orow + r;
                const float bv = bias[o];
                float sum4 = 0.f, ssq4 = 0.f;
                #pragma unroll
                for (int j = 0; j < 4; ++j) {
                    const int l = l0 + wn * 64 + j * 16 + l15;
                    float v = acc[i][j][r] + bv;
                    if (MODE == 1) v += resid[((size_t)b * C_ + o) * L_ + l];
                    out[((size_t)b * M + o) * L_ + l] = v;
                    if (MODE == 1) { sum4 += v; ssq4 = fmaf(v, v, ssq4); }
                }
                if constexpr (MODE == 1) {
                    #pragma unroll
                    for (int m = 1; m < 16; m <<= 1) {
                        sum4 += __shfl_xor(sum4, m);
                        ssq4 += __shfl_xor(ssq4, m);
                    }
                    if (l15 == 0) {
                        atomicAdd(&stt[b * C_ + o].x, sum4);
                        atomicAdd(&stt[b * C_ + o].y, ssq4);
                    }
                }
            }
        }
    } else {
        __syncthreads();
        short* Ts = (short*)lds;
        // q rows pre-scaled by log2(e)/sqrt(32): attn uses exp2 directly
        const float qscale = (MODE == 0 && o0 < 256) ? 0.25509964473787f : 1.0f;
        #pragma unroll
        for (int i = 0; i < 4; ++i) {
            #pragma unroll
            for (int rr = 0; rr < 2; ++rr) {
                const int ol = wm * 64 + i * 16 + orow + rr * 2;
                const float bv0 = bias[o0 + ol];
                const float bv1 = bias[o0 + ol + 1];
                #pragma unroll
                for (int j = 0; j < 4; ++j) {
                    const int ll = wn * 64 + j * 16 + l15;
                    float v0 = acc[i][j][rr * 2 + 0] + bv0;
                    float v1 = acc[i][j][rr * 2 + 1] + bv1;
                    if (MODE == 2) { v0 = gelu_fast(v0); v1 = gelu_fast(v1); }
                    if (MODE == 0) { v0 *= qscale; v1 *= qscale; }
                    *(unsigned*)&Ts[ll * 136 + ol] = pkt(v0, v1);
                }
            }
        }
        __syncthreads();
        if constexpr (MODE == 2) {
            short* ht = (short*)outp;
            #pragma unroll
            for (int it = 0; it < 8; ++it) {
                int idx = t + it * 256;
                int ll = idx >> 4, ck = (idx & 15) * 8;
                short8 v = *(const short8*)(Ts + ll * 136 + ck);
                *(short8*)(ht + ((size_t)b * L_ + l0 + ll) * HID + o0 + ck) = v;
            }
        } else {
            short* qkv = (short*)outp;
            #pragma unroll
            for (int it = 0; it < 8; ++it) {
                int idx = t + it * 256;
                int hb = idx >> 9, rem = idx & 511;
                int ll = rem >> 2, dk = (rem & 3) * 8;
                short8 v = *(const short8*)(Ts + ll * 136 + hb * 32 + dk);
                int og = o0 + hb * 32;
                int part = og >> 8, h = (og & 255) >> 5;
                short* dst = qkv + (size_t)part * ((size_t)B_ * NH * L_ * HD)
                           + (((size_t)(b * NH + h) * L_ + l0 + ll) * HD + dk);
                *(short8*)dst = v;
            }
        }
    }
}

// ---------------------------------------------------------------------------
// MFMA windowed attention, no-max softmax in exp2 domain (Q pre-scaled by
// log2e/sqrt32). K direct-from-global with pinned one-tile prefetch. P packed
// via single v_perm_b32 truncation. Softmax denominator computed ON THE MFMA
// PIPE via a virtual all-ones V-row (constant A-fragment, output row 32).
// LDS 32KB (Vt+Pl).
// ---------------------------------------------------------------------------
__global__ __launch_bounds__(256)
void attn_k(const short* __restrict__ q, const short* __restrict__ k,
            const short* __restrict__ v, short* __restrict__ win_out)
{
    __shared__ __align__(16) short Vt[32][256];     // [d][k], scattered granule
    __shared__ __align__(16) short Pl[4][64][32];   // per-wave [q][k], ^((row>>1)&3)

    const int n = blockIdx.x, h = blockIdx.y, b = blockIdx.z;
    const int start = n * STR;
    const int t = threadIdx.x;
    const int lane = t & 63, w = t >> 6;
    const int l15 = lane & 15, kb = lane >> 4;
    const int csw = (l15 >> 1) & 3;
    const size_t hbase = (size_t)(b * NH + h) * L_ * HD;

    {
        int l = start + t; if (l > L_ - 1) l = L_ - 1;
        const short8* gv = (const short8*)&v[hbase + (size_t)l * HD];
        short8 v0 = gv[0], v1 = gv[1], v2 = gv[2], v3 = gv[3];
        const int g = t >> 3, tl = t & 7;
        #pragma unroll
        for (int e = 0; e < 8; ++e) {
            int pc = ((g & 24) | ((g ^ e) & 7)) * 8 + tl;
            Vt[e][pc]      = v0[e];
            Vt[8 + e][pc]  = v1[e];
            Vt[16 + e][pc] = v2[e];
            Vt[24 + e][pc] = v3[e];
        }
    }

    short8 qf[4];
    #pragma unroll
    for (int j = 0; j < 4; ++j) {
        int lq = start + w * 64 + j * 16 + l15; if (lq > L_ - 1) lq = L_ - 1;
        qf[j] = *(const short8*)&q[hbase + (size_t)lq * HD + kb * 8];
    }
    __syncthreads();

    const bool domask = (start + WIN > L_);
    f32x4 ot[2][4] = {};
    f32x4 os[4] = {};                 // denominator row (virtual V-row of 1s)
    const f32x4 zacc = {};

    // constant A-fragment: row 0 (l15==0) = bf16 1.0 across all 32 k-slots
    short8 va2;
    #pragma unroll
    for (int e = 0; e < 8; ++e) va2[e] = (l15 == 0) ? (short)0x3F80 : (short)0;

    short8 ka[2];
    #pragma unroll
    for (int i = 0; i < 2; ++i) {
        int lr = start + i * 16 + l15; if (lr > L_ - 1) lr = L_ - 1;
        ka[i] = *(const short8*)&k[hbase + (size_t)lr * HD + kb * 8];
    }

    #pragma unroll 1
    for (int kt = 0; kt < 8; ++kt) {
        f32x4 st[2][4];
        #pragma unroll
        for (int i = 0; i < 2; ++i)
            #pragma unroll
            for (int j = 0; j < 4; ++j)
                st[i][j] = __builtin_amdgcn_mfma_f32_16x16x32_bf16(ka[i], qf[j], zacc, 0, 0, 0);

        // prefetch K for next tile; latency hides under softmax/PV below
        short8 kan[2];
        {
            int kt2 = (kt < 7) ? kt + 1 : 7;
            #pragma unroll
            for (int i = 0; i < 2; ++i) {
                int lr = start + kt2 * 32 + i * 16 + l15; if (lr > L_ - 1) lr = L_ - 1;
                kan[i] = *(const short8*)&k[hbase + (size_t)lr * HD + kb * 8];
            }
        }

        if (domask) {
            #pragma unroll
            for (int i = 0; i < 2; ++i)
                #pragma unroll
                for (int r = 0; r < 4; ++r) {
                    int kp = start + kt * 32 + i * 16 + kb * 4 + r;
                    if (kp >= L_) {
                        #pragma unroll
                        for (int j = 0; j < 4; ++j) st[i][j][r] = -1e30f;
                    }
                }
        }

        #pragma unroll
        for (int j = 0; j < 4; ++j) {
            #pragma unroll
            for (int i = 0; i < 2; ++i) {
                float p0 = __builtin_amdgcn_exp2f(st[i][j][0]);
                float p1 = __builtin_amdgcn_exp2f(st[i][j][1]);
                float p2 = __builtin_amdgcn_exp2f(st[i][j][2]);
                float p3 = __builtin_amdgcn_exp2f(st[i][j][3]);
                uint2 u;
                u.x = pkt(p0, p1);
                u.y = pkt(p2, p3);
                int pg = ((2 * i + (kb >> 1)) ^ csw) * 8 + (kb & 1) * 4;
                *(uint2*)&Pl[w][j * 16 + l15][pg] = u;
            }
        }
        asm volatile("s_waitcnt lgkmcnt(0)" ::: "memory");
        __builtin_amdgcn_sched_barrier(0);

        short8 pb[4], va[2];
        #pragma unroll
        for (int j = 0; j < 4; ++j)
            pb[j] = *(const short8*)&Pl[w][j * 16 + l15][(kb ^ csw) * 8];
        #pragma unroll
        for (int i = 0; i < 2; ++i) {
            int g = kt * 4 + kb;
            int vg = (g & 24) | ((g ^ l15) & 7);
            va[i] = *(const short8*)&Vt[i * 16 + l15][vg * 8];
        }
        #pragma unroll
        for (int i = 0; i < 2; ++i)
            #pragma unroll
            for (int j = 0; j < 4; ++j)
                ot[i][j] = __builtin_amdgcn_mfma_f32_16x16x32_bf16(va[i], pb[j], ot[i][j], 0, 0, 0);
        #pragma unroll
        for (int j = 0; j < 4; ++j)
            os[j] = __builtin_amdgcn_mfma_f32_16x16x32_bf16(va2, pb[j], os[j], 0, 0, 0);

        ka[0] = kan[0]; ka[1] = kan[1];
    }

    float sc[4];
    #pragma unroll
    for (int j = 0; j < 4; ++j) {
        // denominator lives in output row 32 -> fragment reg 0 of kb==0 lanes
        float s = __shfl(os[j][0], l15);
        int lq = start + w * 64 + j * 16 + l15;
        int nhi = lq / STR;
        int nlo = (lq >= WIN) ? ((lq - WIN) / STR + 1) : 0;
        sc[j] = 1.0f / (s * (float)(nhi - nlo + 1));
    }

    short* base = win_out + (((size_t)(b * NH + h) * NWIN + n) * WIN) * HD;
    #pragma unroll
    for (int i = 0; i < 2; ++i)
        #pragma unroll
        for (int j = 0; j < 4; ++j) {
            int qrow = w * 64 + j * 16 + l15;
            int d    = i * 16 + kb * 4;
            f32x4 o = ot[i][j];
            uint2 u;
            u.x = pkt(o[0] * sc[j], o[1] * sc[j]);
            u.y = pkt(o[2] * sc[j], o[3] * sc[j]);
            *(uint2*)&base[(size_t)qrow * HD + d] = u;
        }
}

// ---------------------------------------------------------------------------
// Transpose+convert: f32 [B][C][L] -> bf16 [B][L][C]; optional +pos or
// instance-norm from raw (sum,ssq) stats.
// ---------------------------------------------------------------------------
__global__ __launch_bounds__(256)
void prep_k(const float* __restrict__ in, const float* __restrict__ pos,
            const float2* __restrict__ stt, short* __restrict__ outT)
{
    __shared__ float T[64][65];
    const int b = blockIdx.z, c0 = blockIdx.y * 64, l0 = blockIdx.x * 64;
    const int t = threadIdx.x;
    #pragma unroll
    for (int it = 0; it < 4; ++it) {
        int idx = t + it * 256;
        int c = idx >> 4, l4 = (idx & 15) * 4;
        float4 v = *(const float4*)&in[((size_t)b * C_ + c0 + c) * L_ + l0 + l4];
        if (stt) {
            float2 ms = stt[b * C_ + c0 + c];
            float mean = ms.x * (1.0f / L_);
            float rstd = rsqrtf(fmaf(-mean, mean, ms.y * (1.0f / L_)) + 1e-5f);
            v.x = (v.x - mean) * rstd; v.y = (v.y - mean) * rstd;
            v.z = (v.z - mean) * rstd; v.w = (v.w - mean) * rstd;
        }
        float p = pos ? pos[c0 + c] : 0.f;
        T[c][l4 + 0] = v.x + p; T[c][l4 + 1] = v.y + p;
        T[c][l4 + 2] = v.z + p; T[c][l4 + 3] = v.w + p;
    }
    __syncthreads();
    #pragma unroll
    for (int it = 0; it < 2; ++it) {
        int idx = t + it * 256;
        int l = idx >> 3, ck = (idx & 7) * 8;
        short8 o;
        #pragma unroll
        for (int j = 0; j < 8; ++j) o[j] = f2b(T[ck + j][l]);
        *(short8*)&outT[((size_t)b * L_ + l0 + l) * C_ + c0 + ck] = o;
    }
}

__global__ __launch_bounds__(256)
void wconv_k(const float* a, const float* b, const float* c, const float* d,
             short* oa, short* ob, short* oc, short* od)
{
    int i = (blockIdx.x * 256 + threadIdx.x) * 8;
    const float* s; short* o; int off;
    if (i < 196608)      { s = a; o = oa; off = i; }
    else if (i < 262144) { s = b; o = ob; off = i - 196608; }
    else if (i < 524288) { s = c; o = oc; off = i - 262144; }
    else                 { s = d; o = od; off = i - 524288; }
    float4 v0 = *(const float4*)(s + off);
    float4 v1 = *(const float4*)(s + off + 4);
    short8 r;
    r[0] = f2b(v0.x); r[1] = f2b(v0.y); r[2] = f2b(v0.z); r[3] = f2b(v0.w);
    r[4] = f2b(v1.x); r[5] = f2b(v1.y); r[6] = f2b(v1.z); r[7] = f2b(v1.w);
    *(short8*)(o + off) = r;
}

// ---------------------------------------------------------------------------
// Final: dst = instance_norm(src) + (add - amean)*arstd, add-stats from raw
// (sum,ssq) buffer.
// ---------------------------------------------------------------------------
__global__ __launch_bounds__(256)
void norm_k(const float* __restrict__ src, const float* __restrict__ add,
            const float2* __restrict__ ast, float* __restrict__ dst)
{
    const int row = blockIdx.x;
    const float* s = src + (size_t)row * L_;
    const int t = threadIdx.x;
    float4 vals[8];
    float sum = 0.f, ssq = 0.f;
    #pragma unroll
    for (int i = 0; i < 8; ++i) {
        float4 vv = *(const float4*)&s[t * 4 + i * 1024];
        vals[i] = vv;
        sum += (vv.x + vv.y) + (vv.z + vv.w);
        ssq += vv.x*vv.x + vv.y*vv.y + vv.z*vv.z + vv.w*vv.w;
    }
    #pragma unroll
    for (int off = 32; off > 0; off >>= 1) {
        sum += __shfl_down(sum, off);
        ssq += __shfl_down(ssq, off);
    }
    __shared__ float rbuf[8];
    __shared__ float s_mean, s_rstd;
    if ((t & 63) == 0) { rbuf[t >> 6] = sum; rbuf[4 + (t >> 6)] = ssq; }
    __syncthreads();
    if (t == 0) {
        float a  = (rbuf[0] + rbuf[1]) + (rbuf[2] + rbuf[3]);
        float q2 = (rbuf[4] + rbuf[5]) + (rbuf[6] + rbuf[7]);
        float mean = a * (1.0f / L_);
        float var  = q2 * (1.0f / L_) - mean * mean;
        s_mean = mean;
        s_rstd = rsqrtf(var + 1e-5f);
    }
    __syncthreads();
    const float mean = s_mean, rstd = s_rstd;
    const float2 msr = ast[row];
    const float amean = msr.x * (1.0f / L_);
    const float arstd = rsqrtf(fmaf(-amean, amean, msr.y * (1.0f / L_)) + 1e-5f);
    float* d = dst + (size_t)row * L_;
    const float* ar = add + (size_t)row * L_;
    #pragma unroll
    for (int i = 0; i < 8; ++i) {
        float4 vv = vals[i];
        float4 av = *(const float4*)&ar[t * 4 + i * 1024];
        vv.x = (vv.x - mean) * rstd + (av.x - amean) * arstd;
        vv.y = (vv.y - mean) * rstd + (av.y - amean) * arstd;
        vv.z = (vv.z - mean) * rstd + (av.z - amean) * arstd;
        vv.w = (vv.w - mean) * rstd + (av.w - amean) * arstd;
        *(float4*)&d[t * 4 + i * 1024] = vv;
    }
}

extern "C" void kernel_launch(void* const* d_in, const int* in_sizes, int n_in,
                              void* d_out, int out_size, void* d_ws, size_t ws_size,
                              hipStream_t stream) {
    const float* x      = (const float*)d_in[0];
    const float* pos    = (const float*)d_in[1];
    const float* w_qkv  = (const float*)d_in[2];
    const float* b_qkv  = (const float*)d_in[3];
    const float* w_out  = (const float*)d_in[4];
    const float* b_out  = (const float*)d_in[5];
    const float* w_mlp1 = (const float*)d_in[6];
    const float* b_mlp1 = (const float*)d_in[7];
    const float* w_mlp2 = (const float*)d_in[8];
    const float* b_mlp2 = (const float*)d_in[9];
    float* out = (float*)d_out;

    constexpr size_t MB = 1u << 20;
    char* w = (char*)d_ws;
    short*  xp_t  = (short*)(w);              // 16MB, dead after mgemm<0>
    short*  qb    = (short*)(w + 16 * MB);    // 48MB q/k/v, dead after attn_k
    short*  winb  = (short*)(w + 64 * MB);    // 21.5MB, dead after mgemm<1>
    float*  yb    = (float*)(w + 88 * MB);    // 32MB raw y, live to end
    short*  y_t   = (short*)(w + 120 * MB);   // 16MB
    short*  h_t   = (short*)(w);              // 64MB overlay [0,64)
    float2* yst   = (float2*)(w + 136 * MB);  // 8KB raw (sum,ssq) stats
    short*  wqb   = (short*)(w + 137 * MB);
    short*  wob   = wqb + 196608;
    short*  wm1b  = wob + 65536;
    short*  wm2b  = wm1b + 262144;

    const size_t SZ = (size_t)B_ * C_ * L_;

    hipMemsetAsync(yst, 0, (size_t)B_ * C_ * sizeof(float2), stream);
    wconv_k<<<384, 256, 0, stream>>>(w_qkv, w_out, w_mlp1, w_mlp2, wqb, wob, wm1b, wm2b);
    prep_k <<<dim3(128, 4, B_), 256, 0, stream>>>(x, pos, nullptr, xp_t);

    mgemm<0><<<dim3(64, 6, B_), 256, 0, stream>>>(wqb, xp_t, b_qkv, nullptr, qb, nullptr);
    attn_k  <<<dim3(NWIN, NH, B_), 256, 0, stream>>>(qb, qb + SZ, qb + 2 * SZ, winb);
    mgemm<1><<<dim3(64, 2, B_), 256, 0, stream>>>(wob, winb, b_out, x, yb, yst);
    prep_k  <<<dim3(128, 4, B_), 256, 0, stream>>>(yb, nullptr, yst, y_t);
    mgemm<2><<<dim3(64, 8, B_), 256, 0, stream>>>(wm1b, y_t, b_mlp1, nullptr, h_t, nullptr);
    mgemm<3><<<dim3(64, 2, B_), 256, 0, stream>>>(wm2b, h_t, b_mlp2, nullptr, out, nullptr);
    norm_k  <<<B_ * C_, 256, 0, stream>>>(out, yb, yst, out);
}

// Round 24
// 168.608 us; speedup vs baseline: 1.1668x; 1.1668x over previous
//
#include <hip/hip_runtime.h>
#include <hip/hip_bf16.h>
#include <math.h>

#define B_   4
#define C_   256
#define L_   8192
#define NH   8
#define HD   32
#define WIN  256
#define STR  192
#define NWIN 43
#define HID  1024

typedef short short8 __attribute__((ext_vector_type(8)));
typedef float f32x4  __attribute__((ext_vector_type(4)));

typedef __attribute__((address_space(3))) unsigned int       as3_u32;
typedef __attribute__((address_space(1))) const unsigned int as1_u32;

__device__ __forceinline__ void gll16(const void* g, void* l) {
    __builtin_amdgcn_global_load_lds((as1_u32*)g, (as3_u32*)l, 16, 0, 0);
}

__device__ __forceinline__ short f2b(float f) {          // f32 -> bf16 RNE
    unsigned u = __builtin_bit_cast(unsigned, f);
    u += 0x7fffu + ((u >> 16) & 1u);
    return (short)(u >> 16);
}
__device__ __forceinline__ float b2f(short s) {
    return __builtin_bit_cast(float, (unsigned)((unsigned short)s) << 16);
}
// single v_perm_b32: pack hi16(a)|hi16(b)<<16 (bf16 TRUNCATION; ~2^-8 rel)
__device__ __forceinline__ unsigned pkt(float a, float b) {
    return __builtin_amdgcn_perm(__builtin_bit_cast(unsigned, b),
                                 __builtin_bit_cast(unsigned, a),
                                 0x07060302u);
}
// tanh-form GELU, exp2-folded constants + raw v_rcp; |err| < ~1e-3
__device__ __forceinline__ float gelu_fast(float x) {
    float t = x * x;
    float u = fmaf(0.1029436f * t, x, 2.3022083f * x);   // coeffs * log2(e)
    return x * __builtin_amdgcn_rcpf(1.0f + __builtin_amdgcn_exp2f(-u));
}

// ---------------------------------------------------------------------------
// bf16 MFMA GEMM, 128x128 tile, BK=64 (2 kk sub-steps of K=32), 4 waves.
// LDS A/B [128 rows][8 chunks of 16B], chunk-swizzled phys = logical ^ (row&7)
// via pre-swizzled global source; LDS dest stays linear for global_load_lds.
// MODE 0: qkv  (M=768,K=256)  -> +bias (q pre-scaled log2e/sqrt32), bf16 qkv
// MODE 1: proj (M=256,K=256)  B = window-combine of win_out (fused comb)
//                             -> +bias+resid, f32 y [b][C][l]
// MODE 2: mlp1 (M=1024,K=256) -> gelu_fast(+bias), bf16 h_t [b][l][HID]
// MODE 3: mlp2 (M=256,K=1024) -> +bias, f32 d_out [b][C][l]
// ---------------------------------------------------------------------------
template<int MODE>
__global__ __launch_bounds__(256)
void mgemm(const short* __restrict__ Wb, const short* __restrict__ Xsrc,
           const float* __restrict__ bias, const float* __restrict__ resid,
           void* __restrict__ outp)
{
    constexpr int K = (MODE == 3) ? 1024 : 256;
    constexpr int M = (MODE == 0) ? 768 : (MODE == 2) ? 1024 : 256;
    constexpr int LDSZ = (MODE == 0 || MODE == 2) ? 34816 : 32768;
    __shared__ __align__(16) char lds[LDSZ];

    const int t    = threadIdx.x;
    const int lane = t & 63, wid = t >> 6;
    const int wm   = wid >> 1, wn = wid & 1;
    const int b    = blockIdx.z;
    const int o0   = blockIdx.y * 128;
    const int l0   = blockIdx.x * 128;
    const int l15  = lane & 15, kb = lane >> 4;

    f32x4 acc[4][4] = {};
    const short* Xb = Xsrc + (size_t)b * L_ * K;

    // MODE 1: per-staged-row window indices (independent of k)
    int pn1[4], pj1[4]; bool ptwo[4];
    if constexpr (MODE == 1) {
        #pragma unroll
        for (int it = 0; it < 4; ++it) {
            int r = (it * 256 + t) >> 3;
            int l = l0 + r;
            int n1 = l / STR;
            pn1[it] = n1; pj1[it] = l - n1 * STR;
            ptwo[it] = (n1 >= 1) && (pj1[it] < WIN - STR);
        }
    }

    for (int c0 = 0; c0 < K; c0 += 64) {
        __syncthreads();
        // ---- stage A (weights) ----
        #pragma unroll
        for (int it = 0; it < 4; ++it) {
            int d = it * 256 + t;
            int r = d >> 3, pc = d & 7;
            int clog = pc ^ (r & 7);
            gll16(Wb + (size_t)(o0 + r) * K + c0 + clog * 8,
                  lds + (it * 256 + wid * 64) * 16);
        }
        // ---- stage B ----
        if constexpr (MODE == 1) {
            #pragma unroll
            for (int it = 0; it < 4; ++it) {
                int d = it * 256 + t;
                int r = d >> 3, pc = d & 7;
                int clog = pc ^ (r & 7);
                int c = c0 + clog * 8;
                int h = c >> 5, dd = c & 31;
                size_t base = ((((size_t)(b * NH + h)) * NWIN + pn1[it]) * WIN + pj1[it]) * HD + dd;
                short8 vv = *(const short8*)&Xsrc[base];
                if (ptwo[it]) {
                    short8 u = *(const short8*)&Xsrc[base - 2048];  // (n1-1, j1+192)
                    #pragma unroll
                    for (int e = 0; e < 8; ++e) vv[e] = f2b(b2f(vv[e]) + b2f(u[e]));
                }
                *(short8*)(lds + 16384 + d * 16) = vv;
            }
        } else {
            #pragma unroll
            for (int it = 0; it < 4; ++it) {
                int d = it * 256 + t;
                int r = d >> 3, pc = d & 7;
                int clog = pc ^ (r & 7);
                gll16(Xb + (size_t)(l0 + r) * K + c0 + clog * 8,
                      lds + 16384 + (it * 256 + wid * 64) * 16);
            }
        }
        __syncthreads();
        // ---- compute: 2 kk sub-steps of 16 MFMA ----
        #pragma unroll
        for (int kk = 0; kk < 2; ++kk) {
            short8 af[4], bf[4];
            #pragma unroll
            for (int i = 0; i < 4; ++i)
                af[i] = *(const short8*)(lds +
                    ((wm * 64 + i * 16 + l15) * 8 + ((kk * 4 + kb) ^ (l15 & 7))) * 16);
            #pragma unroll
            for (int j = 0; j < 4; ++j)
                bf[j] = *(const short8*)(lds + 16384 +
                    ((wn * 64 + j * 16 + l15) * 8 + ((kk * 4 + kb) ^ (l15 & 7))) * 16);
            #pragma unroll
            for (int i = 0; i < 4; ++i)
                #pragma unroll
                for (int j = 0; j < 4; ++j)
                    acc[i][j] = __builtin_amdgcn_mfma_f32_16x16x32_bf16(af[i], bf[j], acc[i][j], 0, 0, 0);
        }
    }

    const int orow = (lane >> 4) * 4;

    if constexpr (MODE == 1 || MODE == 3) {
        float* out = (float*)outp;
        #pragma unroll
        for (int i = 0; i < 4; ++i) {
            #pragma unroll
            for (int r = 0; r < 4; ++r) {
                const int o = o0 + wm * 64 + i * 16 + orow + r;
                const float bv = bias[o];
                #pragma unroll
                for (int j = 0; j < 4; ++j) {
                    const int l = l0 + wn * 64 + j * 16 + l15;
                    float v = acc[i][j][r] + bv;
                    if (MODE == 1) v += resid[((size_t)b * C_ + o) * L_ + l];
                    out[((size_t)b * M + o) * L_ + l] = v;
                }
            }
        }
    } else {
        __syncthreads();
        short* Ts = (short*)lds;
        // q rows pre-scaled by log2(e)/sqrt(32): attn uses exp2 directly
        const float qscale = (MODE == 0 && o0 < 256) ? 0.25509964473787f : 1.0f;
        #pragma unroll
        for (int i = 0; i < 4; ++i) {
            #pragma unroll
            for (int rr = 0; rr < 2; ++rr) {
                const int ol = wm * 64 + i * 16 + orow + rr * 2;
                const float bv0 = bias[o0 + ol];
                const float bv1 = bias[o0 + ol + 1];
                #pragma unroll
                for (int j = 0; j < 4; ++j) {
                    const int ll = wn * 64 + j * 16 + l15;
                    float v0 = acc[i][j][rr * 2 + 0] + bv0;
                    float v1 = acc[i][j][rr * 2 + 1] + bv1;
                    if (MODE == 2) { v0 = gelu_fast(v0); v1 = gelu_fast(v1); }
                    if (MODE == 0) { v0 *= qscale; v1 *= qscale; }
                    *(unsigned*)&Ts[ll * 136 + ol] = pkt(v0, v1);
                }
            }
        }
        __syncthreads();
        if constexpr (MODE == 2) {
            short* ht = (short*)outp;
            #pragma unroll
            for (int it = 0; it < 8; ++it) {
                int idx = t + it * 256;
                int ll = idx >> 4, ck = (idx & 15) * 8;
                short8 v = *(const short8*)(Ts + ll * 136 + ck);
                *(short8*)(ht + ((size_t)b * L_ + l0 + ll) * HID + o0 + ck) = v;
            }
        } else {
            short* qkv = (short*)outp;
            #pragma unroll
            for (int it = 0; it < 8; ++it) {
                int idx = t + it * 256;
                int hb = idx >> 9, rem = idx & 511;
                int ll = rem >> 2, dk = (rem & 3) * 8;
                short8 v = *(const short8*)(Ts + ll * 136 + hb * 32 + dk);
                int og = o0 + hb * 32;
                int part = og >> 8, h = (og & 255) >> 5;
                short* dst = qkv + (size_t)part * ((size_t)B_ * NH * L_ * HD)
                           + (((size_t)(b * NH + h) * L_ + l0 + ll) * HD + dk);
                *(short8*)dst = v;
            }
        }
    }
}

// ---------------------------------------------------------------------------
// MFMA windowed attention, no-max softmax in exp2 domain (Q pre-scaled by
// log2e/sqrt32). K direct-from-global with pinned one-tile prefetch. P packed
// via single v_perm_b32 truncation. Softmax denominator computed ON THE MFMA
// PIPE via a virtual all-ones V-row (constant A-fragment, output row 32).
// LDS 32KB (Vt+Pl).
// ---------------------------------------------------------------------------
__global__ __launch_bounds__(256)
void attn_k(const short* __restrict__ q, const short* __restrict__ k,
            const short* __restrict__ v, short* __restrict__ win_out)
{
    __shared__ __align__(16) short Vt[32][256];     // [d][k], scattered granule
    __shared__ __align__(16) short Pl[4][64][32];   // per-wave [q][k], ^((row>>1)&3)

    const int n = blockIdx.x, h = blockIdx.y, b = blockIdx.z;
    const int start = n * STR;
    const int t = threadIdx.x;
    const int lane = t & 63, w = t >> 6;
    const int l15 = lane & 15, kb = lane >> 4;
    const int csw = (l15 >> 1) & 3;
    const size_t hbase = (size_t)(b * NH + h) * L_ * HD;

    {
        int l = start + t; if (l > L_ - 1) l = L_ - 1;
        const short8* gv = (const short8*)&v[hbase + (size_t)l * HD];
        short8 v0 = gv[0], v1 = gv[1], v2 = gv[2], v3 = gv[3];
        const int g = t >> 3, tl = t & 7;
        #pragma unroll
        for (int e = 0; e < 8; ++e) {
            int pc = ((g & 24) | ((g ^ e) & 7)) * 8 + tl;
            Vt[e][pc]      = v0[e];
            Vt[8 + e][pc]  = v1[e];
            Vt[16 + e][pc] = v2[e];
            Vt[24 + e][pc] = v3[e];
        }
    }

    short8 qf[4];
    #pragma unroll
    for (int j = 0; j < 4; ++j) {
        int lq = start + w * 64 + j * 16 + l15; if (lq > L_ - 1) lq = L_ - 1;
        qf[j] = *(const short8*)&q[hbase + (size_t)lq * HD + kb * 8];
    }
    __syncthreads();

    const bool domask = (start + WIN > L_);
    f32x4 ot[2][4] = {};
    f32x4 os[4] = {};                 // denominator row (virtual V-row of 1s)
    const f32x4 zacc = {};

    // constant A-fragment: row 0 (l15==0) = bf16 1.0 across all 32 k-slots
    short8 va2;
    #pragma unroll
    for (int e = 0; e < 8; ++e) va2[e] = (l15 == 0) ? (short)0x3F80 : (short)0;

    short8 ka[2];
    #pragma unroll
    for (int i = 0; i < 2; ++i) {
        int lr = start + i * 16 + l15; if (lr > L_ - 1) lr = L_ - 1;
        ka[i] = *(const short8*)&k[hbase + (size_t)lr * HD + kb * 8];
    }

    #pragma unroll 1
    for (int kt = 0; kt < 8; ++kt) {
        f32x4 st[2][4];
        #pragma unroll
        for (int i = 0; i < 2; ++i)
            #pragma unroll
            for (int j = 0; j < 4; ++j)
                st[i][j] = __builtin_amdgcn_mfma_f32_16x16x32_bf16(ka[i], qf[j], zacc, 0, 0, 0);

        // prefetch K for next tile; latency hides under softmax/PV below
        short8 kan[2];
        {
            int kt2 = (kt < 7) ? kt + 1 : 7;
            #pragma unroll
            for (int i = 0; i < 2; ++i) {
                int lr = start + kt2 * 32 + i * 16 + l15; if (lr > L_ - 1) lr = L_ - 1;
                kan[i] = *(const short8*)&k[hbase + (size_t)lr * HD + kb * 8];
            }
        }

        if (domask) {
            #pragma unroll
            for (int i = 0; i < 2; ++i)
                #pragma unroll
                for (int r = 0; r < 4; ++r) {
                    int kp = start + kt * 32 + i * 16 + kb * 4 + r;
                    if (kp >= L_) {
                        #pragma unroll
                        for (int j = 0; j < 4; ++j) st[i][j][r] = -1e30f;
                    }
                }
        }

        #pragma unroll
        for (int j = 0; j < 4; ++j) {
            #pragma unroll
            for (int i = 0; i < 2; ++i) {
                float p0 = __builtin_amdgcn_exp2f(st[i][j][0]);
                float p1 = __builtin_amdgcn_exp2f(st[i][j][1]);
                float p2 = __builtin_amdgcn_exp2f(st[i][j][2]);
                float p3 = __builtin_amdgcn_exp2f(st[i][j][3]);
                uint2 u;
                u.x = pkt(p0, p1);
                u.y = pkt(p2, p3);
                int pg = ((2 * i + (kb >> 1)) ^ csw) * 8 + (kb & 1) * 4;
                *(uint2*)&Pl[w][j * 16 + l15][pg] = u;
            }
        }
        asm volatile("s_waitcnt lgkmcnt(0)" ::: "memory");
        __builtin_amdgcn_sched_barrier(0);

        short8 pb[4], va[2];
        #pragma unroll
        for (int j = 0; j < 4; ++j)
            pb[j] = *(const short8*)&Pl[w][j * 16 + l15][(kb ^ csw) * 8];
        #pragma unroll
        for (int i = 0; i < 2; ++i) {
            int g = kt * 4 + kb;
            int vg = (g & 24) | ((g ^ l15) & 7);
            va[i] = *(const short8*)&Vt[i * 16 + l15][vg * 8];
        }
        #pragma unroll
        for (int i = 0; i < 2; ++i)
            #pragma unroll
            for (int j = 0; j < 4; ++j)
                ot[i][j] = __builtin_amdgcn_mfma_f32_16x16x32_bf16(va[i], pb[j], ot[i][j], 0, 0, 0);
        #pragma unroll
        for (int j = 0; j < 4; ++j)
            os[j] = __builtin_amdgcn_mfma_f32_16x16x32_bf16(va2, pb[j], os[j], 0, 0, 0);

        ka[0] = kan[0]; ka[1] = kan[1];
    }

    float sc[4];
    #pragma unroll
    for (int j = 0; j < 4; ++j) {
        // denominator lives in output row 32 -> fragment reg 0 of kb==0 lanes
        float s = __shfl(os[j][0], l15);
        int lq = start + w * 64 + j * 16 + l15;
        int nhi = lq / STR;
        int nlo = (lq >= WIN) ? ((lq - WIN) / STR + 1) : 0;
        sc[j] = 1.0f / (s * (float)(nhi - nlo + 1));
    }

    short* base = win_out + (((size_t)(b * NH + h) * NWIN + n) * WIN) * HD;
    #pragma unroll
    for (int i = 0; i < 2; ++i)
        #pragma unroll
        for (int j = 0; j < 4; ++j) {
            int qrow = w * 64 + j * 16 + l15;
            int d    = i * 16 + kb * 4;
            f32x4 o = ot[i][j];
            uint2 u;
            u.x = pkt(o[0] * sc[j], o[1] * sc[j]);
            u.y = pkt(o[2] * sc[j], o[3] * sc[j]);
            *(uint2*)&base[(size_t)qrow * HD + d] = u;
        }
}

// ---------------------------------------------------------------------------
__global__ __launch_bounds__(256)
void stats_k(const float* __restrict__ src, float2* __restrict__ stt)
{
    const int row = blockIdx.x;
    const float* s = src + (size_t)row * L_;
    const int t = threadIdx.x;
    float sum = 0.f, ssq = 0.f;
    #pragma unroll
    for (int i = 0; i < 8; ++i) {
        float4 vv = *(const float4*)&s[t * 4 + i * 1024];
        sum += (vv.x + vv.y) + (vv.z + vv.w);
        ssq += vv.x*vv.x + vv.y*vv.y + vv.z*vv.z + vv.w*vv.w;
    }
    #pragma unroll
    for (int off = 32; off > 0; off >>= 1) {
        sum += __shfl_down(sum, off);
        ssq += __shfl_down(ssq, off);
    }
    __shared__ float rbuf[8];
    if ((t & 63) == 0) { rbuf[t >> 6] = sum; rbuf[4 + (t >> 6)] = ssq; }
    __syncthreads();
    if (t == 0) {
        float a  = (rbuf[0] + rbuf[1]) + (rbuf[2] + rbuf[3]);
        float q2 = (rbuf[4] + rbuf[5]) + (rbuf[6] + rbuf[7]);
        float mean = a * (1.0f / L_);
        float var  = q2 * (1.0f / L_) - mean * mean;
        stt[row] = make_float2(mean, rsqrtf(var + 1e-5f));
    }
}

__global__ __launch_bounds__(256)
void prep_k(const float* __restrict__ in, const float* __restrict__ pos,
            const float2* __restrict__ stt, short* __restrict__ outT)
{
    __shared__ float T[64][65];
    const int b = blockIdx.z, c0 = blockIdx.y * 64, l0 = blockIdx.x * 64;
    const int t = threadIdx.x;
    #pragma unroll
    for (int it = 0; it < 4; ++it) {
        int idx = t + it * 256;
        int c = idx >> 4, l4 = (idx & 15) * 4;
        float4 v = *(const float4*)&in[((size_t)b * C_ + c0 + c) * L_ + l0 + l4];
        if (stt) {
            float2 ms = stt[b * C_ + c0 + c];
            v.x = (v.x - ms.x) * ms.y; v.y = (v.y - ms.x) * ms.y;
            v.z = (v.z - ms.x) * ms.y; v.w = (v.w - ms.x) * ms.y;
        }
        float p = pos ? pos[c0 + c] : 0.f;
        T[c][l4 + 0] = v.x + p; T[c][l4 + 1] = v.y + p;
        T[c][l4 + 2] = v.z + p; T[c][l4 + 3] = v.w + p;
    }
    __syncthreads();
    #pragma unroll
    for (int it = 0; it < 2; ++it) {
        int idx = t + it * 256;
        int l = idx >> 3, ck = (idx & 7) * 8;
        short8 o;
        #pragma unroll
        for (int j = 0; j < 8; ++j) o[j] = f2b(T[ck + j][l]);
        *(short8*)&outT[((size_t)b * L_ + l0 + l) * C_ + c0 + ck] = o;
    }
}

__global__ __launch_bounds__(256)
void wconv_k(const float* a, const float* b, const float* c, const float* d,
             short* oa, short* ob, short* oc, short* od)
{
    int i = (blockIdx.x * 256 + threadIdx.x) * 8;
    const float* s; short* o; int off;
    if (i < 196608)      { s = a; o = oa; off = i; }
    else if (i < 262144) { s = b; o = ob; off = i - 196608; }
    else if (i < 524288) { s = c; o = oc; off = i - 262144; }
    else                 { s = d; o = od; off = i - 524288; }
    float4 v0 = *(const float4*)(s + off);
    float4 v1 = *(const float4*)(s + off + 4);
    short8 r;
    r[0] = f2b(v0.x); r[1] = f2b(v0.y); r[2] = f2b(v0.z); r[3] = f2b(v0.w);
    r[4] = f2b(v1.x); r[5] = f2b(v1.y); r[6] = f2b(v1.z); r[7] = f2b(v1.w);
    *(short8*)(o + off) = r;
}

__global__ __launch_bounds__(256)
void norm_k(const float* __restrict__ src, const float* __restrict__ add,
            const float2* __restrict__ ast, float* __restrict__ dst)
{
    const int row = blockIdx.x;
    const float* s = src + (size_t)row * L_;
    const int t = threadIdx.x;
    float4 vals[8];
    float sum = 0.f, ssq = 0.f;
    #pragma unroll
    for (int i = 0; i < 8; ++i) {
        float4 vv = *(const float4*)&s[t * 4 + i * 1024];
        vals[i] = vv;
        sum += (vv.x + vv.y) + (vv.z + vv.w);
        ssq += vv.x*vv.x + vv.y*vv.y + vv.z*vv.z + vv.w*vv.w;
    }
    #pragma unroll
    for (int off = 32; off > 0; off >>= 1) {
        sum += __shfl_down(sum, off);
        ssq += __shfl_down(ssq, off);
    }
    __shared__ float rbuf[8];
    __shared__ float s_mean, s_rstd;
    if ((t & 63) == 0) { rbuf[t >> 6] = sum; rbuf[4 + (t >> 6)] = ssq; }
    __syncthreads();
    if (t == 0) {
        float a  = (rbuf[0] + rbuf[1]) + (rbuf[2] + rbuf[3]);
        float q2 = (rbuf[4] + rbuf[5]) + (rbuf[6] + rbuf[7]);
        float mean = a * (1.0f / L_);
        float var  = q2 * (1.0f / L_) - mean * mean;
        s_mean = mean;
        s_rstd = rsqrtf(var + 1e-5f);
    }
    __syncthreads();
    const float mean = s_mean, rstd = s_rstd;
    const float2 ms = ast[row];
    float* d = dst + (size_t)row * L_;
    const float* ar = add + (size_t)row * L_;
    #pragma unroll
    for (int i = 0; i < 8; ++i) {
        float4 vv = vals[i];
        float4 av = *(const float4*)&ar[t * 4 + i * 1024];
        vv.x = (vv.x - mean) * rstd + (av.x - ms.x) * ms.y;
        vv.y = (vv.y - mean) * rstd + (av.y - ms.x) * ms.y;
        vv.z = (vv.z - mean) * rstd + (av.z - ms.x) * ms.y;
        vv.w = (vv.w - mean) * rstd + (av.w - ms.x) * ms.y;
        *(float4*)&d[t * 4 + i * 1024] = vv;
    }
}

extern "C" void kernel_launch(void* const* d_in, const int* in_sizes, int n_in,
                              void* d_out, int out_size, void* d_ws, size_t ws_size,
                              hipStream_t stream) {
    const float* x      = (const float*)d_in[0];
    const float* pos    = (const float*)d_in[1];
    const float* w_qkv  = (const float*)d_in[2];
    const float* b_qkv  = (const float*)d_in[3];
    const float* w_out  = (const float*)d_in[4];
    const float* b_out  = (const float*)d_in[5];
    const float* w_mlp1 = (const float*)d_in[6];
    const float* b_mlp1 = (const float*)d_in[7];
    const float* w_mlp2 = (const float*)d_in[8];
    const float* b_mlp2 = (const float*)d_in[9];
    float* out = (float*)d_out;

    constexpr size_t MB = 1u << 20;
    char* w = (char*)d_ws;
    short*  xp_t  = (short*)(w);              // 16MB, dead after mgemm<0>
    short*  qb    = (short*)(w + 16 * MB);    // 48MB q/k/v, dead after attn_k
    short*  winb  = (short*)(w + 64 * MB);    // 21.5MB, dead after mgemm<1>
    float*  yb    = (float*)(w + 88 * MB);    // 32MB raw y, live to end
    short*  y_t   = (short*)(w + 120 * MB);   // 16MB
    short*  h_t   = (short*)(w);              // 64MB overlay [0,64)
    float2* yst   = (float2*)(w + 136 * MB);  // 8KB stats
    short*  wqb   = (short*)(w + 137 * MB);
    short*  wob   = wqb + 196608;
    short*  wm1b  = wob + 65536;
    short*  wm2b  = wm1b + 262144;

    const size_t SZ = (size_t)B_ * C_ * L_;

    wconv_k<<<384, 256, 0, stream>>>(w_qkv, w_out, w_mlp1, w_mlp2, wqb, wob, wm1b, wm2b);
    prep_k <<<dim3(128, 4, B_), 256, 0, stream>>>(x, pos, nullptr, xp_t);

    mgemm<0><<<dim3(64, 6, B_), 256, 0, stream>>>(wqb, xp_t, b_qkv, nullptr, qb);
    attn_k  <<<dim3(NWIN, NH, B_), 256, 0, stream>>>(qb, qb + SZ, qb + 2 * SZ, winb);
    mgemm<1><<<dim3(64, 2, B_), 256, 0, stream>>>(wob, winb, b_out, x, yb);
    stats_k <<<B_ * C_, 256, 0, stream>>>(yb, yst);
    prep_k  <<<dim3(128, 4, B_), 256, 0, stream>>>(yb, nullptr, yst, y_t);
    mgemm<2><<<dim3(64, 8, B_), 256, 0, stream>>>(wm1b, y_t, b_mlp1, nullptr, h_t);
    mgemm<3><<<dim3(64, 2, B_), 256, 0, stream>>>(wm2b, h_t, b_mlp2, nullptr, out);
    norm_k  <<<B_ * C_, 256, 0, stream>>>(out, yb, yst, out);
}